// Round 7
// baseline (309.606 us; speedup 1.0000x reference)
//
#include <hip/hip_runtime.h>
#include <hip/hip_bf16.h>

#define BSZ 2
#define SEQ 2048
#define DIMN 1024
#define NH 16
#define DH 64
#define LOG2E 1.4426950408889634f

typedef unsigned short ushort_t;
typedef __attribute__((ext_vector_type(8))) short short8;
typedef __attribute__((ext_vector_type(4))) short short4v;
typedef __attribute__((ext_vector_type(4))) float float4v;

__device__ __forceinline__ ushort_t f2bf(float f) {
    union { float f; unsigned int u; } c; c.f = f;
    return (ushort_t)((c.u + 0x8000u) >> 16);
}
// packed 2xf32 -> 2xbf16 (v_cvt_pk_bf16_f32)
__device__ __forceinline__ unsigned int pkbf(float a, float b) {
    __hip_bfloat162 h = __float22bfloat162_rn(make_float2(a, b));
    unsigned int u; __builtin_memcpy(&u, &h, 4); return u;
}
__device__ __forceinline__ void async_cp16(const ushort_t* g, ushort_t* l) {
    __builtin_amdgcn_global_load_lds((const __attribute__((address_space(1))) void*)g,
                                     (__attribute__((address_space(3))) void*)l, 16, 0, 0);
}

// ---------------- weight pre-convert f32 -> bf16 (4 matrices, 1Mi each) -------------
__global__ __launch_bounds__(256) void cvt_w(
    const float* __restrict__ w0, const float* __restrict__ w1,
    const float* __restrict__ w2, const float* __restrict__ w3,
    ushort_t* __restrict__ o0, ushort_t* __restrict__ o1,
    ushort_t* __restrict__ o2, ushort_t* __restrict__ o3)
{
    const float* s; ushort_t* d;
    switch (blockIdx.y) {
        case 0: s = w0; d = o0; break;
        case 1: s = w1; d = o1; break;
        case 2: s = w2; d = o2; break;
        default: s = w3; d = o3; break;
    }
    int i = (blockIdx.x * 256 + threadIdx.x) * 4;
    float4v v = *(const float4v*)(s + i);
    uint2 o; o.x = pkbf(v[0], v[1]); o.y = pkbf(v[2], v[3]);
    *(uint2*)(d + i) = o;
}

// ---------------- QKV GEMM: A f32 (reg+pk-cvt, padded As), W bf16 async -------------
// N axis 3072: [0,1024) Q (log2-domain scale), [1024,2048) K, [2048,3072) V^T out.
__global__ __launch_bounds__(256) void gemm_qkv(
    const float* __restrict__ xq, const float* __restrict__ xk, const float* __restrict__ xv,
    const ushort_t* __restrict__ Wq, const ushort_t* __restrict__ Wk, const ushort_t* __restrict__ Wv,
    const float* __restrict__ qb, const float* __restrict__ kb, const float* __restrict__ vb,
    ushort_t* __restrict__ Qp, ushort_t* __restrict__ Kp, ushort_t* __restrict__ VpT)
{
    __shared__ ushort_t As[128 * 40];   // padded stride 40 (20 dw): conflict-free frags
    __shared__ ushort_t Bs[128 * 32];   // unpadded: async-contiguous
    const int tid  = threadIdx.x;
    const int lane = tid & 63;
    const int w    = tid >> 6;
    const int wm   = w >> 1, wn = w & 1;
    const int quad = lane >> 4;
    const int l16  = lane & 15;
    const int mBase = blockIdx.y * 128;
    const int nGlob = blockIdx.x * 128;
    const int z     = nGlob >> 10;
    const int nBase = nGlob & 1023;
    const float*    A    = (z == 0) ? xq : (z == 1) ? xk : xv;
    const ushort_t* W    = (z == 0) ? Wq : (z == 1) ? Wk : Wv;
    const float*    bias = (z == 0) ? qb : (z == 1) ? kb : vb;

    float4v acc[4][4];
    const float4v z4 = {0.f, 0.f, 0.f, 0.f};
#pragma unroll
    for (int i = 0; i < 4; ++i)
#pragma unroll
        for (int j = 0; j < 4; ++j) acc[i][j] = z4;

    for (int k0 = 0; k0 < 1024; k0 += 32) {
        float4v a0[2], a1[2];
#pragma unroll
        for (int it = 0; it < 2; ++it) {
            int c = it * 256 + tid, row = c >> 2, col = (c & 3) * 8;
            const float* g = A + (size_t)(mBase + row) * 1024 + k0 + col;
            a0[it] = *(const float4v*)g; a1[it] = *(const float4v*)(g + 4);
        }
        __syncthreads();   // prev-tile frag reads done
#pragma unroll
        for (int it = 0; it < 2; ++it) {
            int c = it * 256 + tid, row = c >> 2, col = (c & 3) * 8;
            async_cp16(W + (size_t)(nBase + row) * 1024 + k0 + col, &Bs[c * 8]);
            uint4 ua;
            ua.x = pkbf(a0[it][0], a0[it][1]); ua.y = pkbf(a0[it][2], a0[it][3]);
            ua.z = pkbf(a1[it][0], a1[it][1]); ua.w = pkbf(a1[it][2], a1[it][3]);
            *(uint4*)&As[row * 40 + col] = ua;
        }
        __syncthreads();   // staging (incl. async) visible

        short8 af[4], bf[4];
#pragma unroll
        for (int mt = 0; mt < 4; ++mt)
            af[mt] = *(const short8*)&As[(wm * 64 + mt * 16 + l16) * 40 + quad * 8];
#pragma unroll
        for (int nt = 0; nt < 4; ++nt)
            bf[nt] = *(const short8*)&Bs[(wn * 64 + nt * 16 + l16) * 32 + quad * 8];
#pragma unroll
        for (int mt = 0; mt < 4; ++mt)
#pragma unroll
            for (int nt = 0; nt < 4; ++nt)
                acc[mt][nt] = __builtin_amdgcn_mfma_f32_16x16x32_bf16(af[mt], bf[nt], acc[mt][nt], 0, 0, 0);
    }

    const float scale = (z == 0) ? 0.125f * LOG2E : 1.0f;
    if (z < 2) {
        ushort_t* C = (z == 0) ? Qp : Kp;
#pragma unroll
        for (int mt = 0; mt < 4; ++mt)
#pragma unroll
            for (int nt = 0; nt < 4; ++nt) {
                int colg = nBase + wn * 64 + nt * 16 + l16;
                float bv = bias[colg];
#pragma unroll
                for (int r = 0; r < 4; ++r) {
                    int rowg = mBase + wm * 64 + mt * 16 + quad * 4 + r;
                    C[(size_t)rowg * 1024 + colg] = f2bf((acc[mt][nt][r] + bv) * scale);
                }
            }
    } else {
        // V transposed out: VpT[((b*16+h)*64+d)*2048 + s], 4 consecutive s per lane
#pragma unroll
        for (int mt = 0; mt < 4; ++mt)
#pragma unroll
            for (int nt = 0; nt < 4; ++nt) {
                int n = nBase + wn * 64 + nt * 16 + l16;
                int hh = n >> 6, d = n & 63;
                float bv = bias[n];
                int rowg = mBase + wm * 64 + mt * 16 + quad * 4;
                int b = rowg >> 11, s = rowg & 2047;
                uint2 pk;
                pk.x = pkbf(acc[mt][nt][0] + bv, acc[mt][nt][1] + bv);
                pk.y = pkbf(acc[mt][nt][2] + bv, acc[mt][nt][3] + bv);
                *(uint2*)&VpT[(((size_t)(b * 16 + hh) * 64 + d) << 11) + s] = pk;
            }
    }
}

// ---------------- O GEMM: tile 128x64, both operands bf16 async (512 blocks) --------
__global__ __launch_bounds__(256) void gemm_o(
    const ushort_t* __restrict__ A, const ushort_t* __restrict__ W,
    const float* __restrict__ bias, float* __restrict__ C)
{
    __shared__ ushort_t As[128 * 32];
    __shared__ ushort_t Bs[64 * 32];
    const int tid  = threadIdx.x;
    const int lane = tid & 63;
    const int w    = tid >> 6;
    const int wm   = w & 1, wn = w >> 1;
    const int quad = lane >> 4;
    const int l16  = lane & 15;
    const int mBase = blockIdx.y * 128;
    const int nBase = blockIdx.x * 64;

    float4v acc[4][2];
    const float4v z4 = {0.f, 0.f, 0.f, 0.f};
#pragma unroll
    for (int mt = 0; mt < 4; ++mt)
#pragma unroll
        for (int nt = 0; nt < 2; ++nt) acc[mt][nt] = z4;

    for (int k0 = 0; k0 < 1024; k0 += 32) {
        __syncthreads();
#pragma unroll
        for (int it = 0; it < 2; ++it) {
            int c = it * 256 + tid, row = c >> 2, col = (c & 3) * 8;
            async_cp16(A + (size_t)(mBase + row) * 1024 + k0 + col, &As[c * 8]);
        }
        {
            int row = tid >> 2, col = (tid & 3) * 8;
            async_cp16(W + (size_t)(nBase + row) * 1024 + k0 + col, &Bs[tid * 8]);
        }
        __syncthreads();

        short8 af[4], bf[2];
#pragma unroll
        for (int mt = 0; mt < 4; ++mt)
            af[mt] = *(const short8*)&As[(wm * 64 + mt * 16 + l16) * 32 + quad * 8];
#pragma unroll
        for (int nt = 0; nt < 2; ++nt)
            bf[nt] = *(const short8*)&Bs[(wn * 32 + nt * 16 + l16) * 32 + quad * 8];
#pragma unroll
        for (int mt = 0; mt < 4; ++mt)
#pragma unroll
            for (int nt = 0; nt < 2; ++nt)
                acc[mt][nt] = __builtin_amdgcn_mfma_f32_16x16x32_bf16(af[mt], bf[nt], acc[mt][nt], 0, 0, 0);
    }

#pragma unroll
    for (int mt = 0; mt < 4; ++mt)
#pragma unroll
        for (int nt = 0; nt < 2; ++nt) {
            int colg = nBase + wn * 32 + nt * 16 + l16;
            float bv = bias[colg];
#pragma unroll
            for (int r = 0; r < 4; ++r) {
                int rowg = mBase + wm * 64 + mt * 16 + quad * 4 + r;
                C[(size_t)rowg * 1024 + colg] = acc[mt][nt][r] + bv;
            }
        }
}

// ---------------- fused flash attention, S^T form, prefetch + alpha-skip ------------
__global__ __launch_bounds__(256) void attn_kernel(
    const ushort_t* __restrict__ Qp, const ushort_t* __restrict__ Kp,
    const ushort_t* __restrict__ VpT, const int* __restrict__ mask,
    ushort_t* __restrict__ Cp)
{
    __shared__ ushort_t QPs[64 * 72];  // Q staging, then reused as Ps
    __shared__ ushort_t Ks[64 * 72];
    __shared__ ushort_t Vt[64 * 72];   // [dim][key]

    const int tid  = threadIdx.x;
    const int lane = tid & 63;
    const int w    = tid >> 6;
    const int quad = lane >> 4;
    const int l16  = lane & 15;
    const int b    = blockIdx.x >> 4;
    const int h    = blockIdx.x & 15;
    const int q0   = blockIdx.y * 64;

    // stage Q (64x64); B-frags hoisted (Q region then recycled as Ps)
    {
        short8 qreg[2];
#pragma unroll
        for (int it = 0; it < 2; ++it) {
            int c = it * 256 + tid, row = c >> 3, col = (c & 7) * 8;
            qreg[it] = *(const short8*)(Qp + (size_t)(b * SEQ + q0 + row) * DIMN + h * DH + col);
        }
#pragma unroll
        for (int it = 0; it < 2; ++it) {
            int c = it * 256 + tid, row = c >> 3, col = (c & 7) * 8;
            *(short8*)&QPs[row * 72 + col] = qreg[it];
        }
    }
    __syncthreads();
    short8 bq[2];
#pragma unroll
    for (int ks = 0; ks < 2; ++ks)
        bq[ks] = *(const short8*)&QPs[(w * 16 + l16) * 72 + ks * 32 + quad * 8];

    const float4v z4 = {0.f, 0.f, 0.f, 0.f};
    float4v Oacc[4];   // O^T: [dim vt*16+quad*4+r][qrow l16]
#pragma unroll
    for (int vt = 0; vt < 4; ++vt) Oacc[vt] = z4;
    float4v Lacc = z4;
    float mrow = -3e38f;

    short8 ones;
#pragma unroll
    for (int j = 0; j < 8; ++j) ones[j] = (short)0x3F80;

    const ushort_t* Vbase = VpT + ((size_t)(b * 16 + h) * 64) * 2048;

    short8 kreg[2], vreg[2];
    int4 mv4[4];
    auto do_prefetch = [&](int kt0) {
#pragma unroll
        for (int it = 0; it < 2; ++it) {
            int c = it * 256 + tid, row = c >> 3, col = (c & 7) * 8;
            kreg[it] = *(const short8*)(Kp + (size_t)(b * SEQ + kt0 + row) * DIMN + h * DH + col);
            vreg[it] = *(const short8*)(Vbase + (size_t)row * 2048 + kt0 + col);
        }
#pragma unroll
        for (int kt = 0; kt < 4; ++kt)
            mv4[kt] = *(const int4*)(mask + b * SEQ + kt0 + kt * 16 + quad * 4);
    };
    do_prefetch(0);

    for (int kt0 = 0; kt0 < SEQ; kt0 += 64) {
        __syncthreads();   // prev-iter LDS reads complete
#pragma unroll
        for (int it = 0; it < 2; ++it) {
            int c = it * 256 + tid, row = c >> 3, col = (c & 7) * 8;
            *(short8*)&Ks[row * 72 + col] = kreg[it];
            *(short8*)&Vt[row * 72 + col] = vreg[it];
        }
        int4 mcur[4];
#pragma unroll
        for (int kt = 0; kt < 4; ++kt) mcur[kt] = mv4[kt];
        __syncthreads();   // staging visible

        if (kt0 + 64 < SEQ) do_prefetch(kt0 + 64);   // overlaps compute below

        // S^T = K.Q^T
        float4v Sv[4];
#pragma unroll
        for (int kt = 0; kt < 4; ++kt) Sv[kt] = z4;
#pragma unroll
        for (int ks = 0; ks < 2; ++ks)
#pragma unroll
            for (int kt = 0; kt < 4; ++kt) {
                short8 ak = *(const short8*)&Ks[(kt * 16 + l16) * 72 + ks * 32 + quad * 8];
                Sv[kt] = __builtin_amdgcn_mfma_f32_16x16x32_bf16(ak, bq[ks], Sv[kt], 0, 0, 0);
            }

        // additive mask
#pragma unroll
        for (int kt = 0; kt < 4; ++kt) {
            int4 mv = mcur[kt];
#pragma unroll
            for (int r = 0; r < 4; ++r) {
                int m = (r == 0) ? mv.x : (r == 1) ? mv.y : (r == 2) ? mv.z : mv.w;
                Sv[kt][r] += (m == 0) ? -1e30f : 0.0f;
            }
        }

        // online softmax (base-2), per-qrow state; wave-coherent alpha-skip
        float mx = Sv[0][0];
#pragma unroll
        for (int kt = 0; kt < 4; ++kt)
#pragma unroll
            for (int r = 0; r < 4; ++r) mx = fmaxf(mx, Sv[kt][r]);
        mx = fmaxf(mx, __shfl_xor(mx, 16));
        mx = fmaxf(mx, __shfl_xor(mx, 32));
        if (__any(mx > mrow)) {
            float mn = fmaxf(mrow, mx);
            float alpha = exp2f(mrow - mn);
            mrow = mn;
#pragma unroll
            for (int vt = 0; vt < 4; ++vt) Oacc[vt] *= alpha;
            Lacc *= alpha;
        }
#pragma unroll
        for (int kt = 0; kt < 4; ++kt)
#pragma unroll
            for (int r = 0; r < 4; ++r) Sv[kt][r] = exp2f(Sv[kt][r] - mrow);

        // P -> Ps[qrow][key] packed b64
#pragma unroll
        for (int kt = 0; kt < 4; ++kt) {
            uint2 pk;
            pk.x = pkbf(Sv[kt][0], Sv[kt][1]);
            pk.y = pkbf(Sv[kt][2], Sv[kt][3]);
            *(uint2*)&QPs[(w * 16 + l16) * 72 + kt * 16 + quad * 4] = pk;
        }

        // O^T += V^T.P^T ; L += 1.P^T
#pragma unroll
        for (int ks = 0; ks < 2; ++ks) {
            short8 bp = *(const short8*)&QPs[(w * 16 + l16) * 72 + ks * 32 + quad * 8];
            Lacc = __builtin_amdgcn_mfma_f32_16x16x32_bf16(ones, bp, Lacc, 0, 0, 0);
#pragma unroll
            for (int vt = 0; vt < 4; ++vt) {
                short8 av = *(const short8*)&Vt[(vt * 16 + l16) * 72 + ks * 32 + quad * 8];
                Oacc[vt] = __builtin_amdgcn_mfma_f32_16x16x32_bf16(av, bp, Oacc[vt], 0, 0, 0);
            }
        }
    }

    // epilogue: O^T -> Cp[qrow][dim], packed 8B stores
    float inv = 1.0f / Lacc[0];
    int row = q0 + w * 16 + l16;
#pragma unroll
    for (int vt = 0; vt < 4; ++vt) {
        uint2 pk;
        pk.x = pkbf(Oacc[vt][0] * inv, Oacc[vt][1] * inv);
        pk.y = pkbf(Oacc[vt][2] * inv, Oacc[vt][3] * inv);
        *(uint2*)&Cp[(size_t)(b * SEQ + row) * DIMN + h * DH + vt * 16 + quad * 4] = pk;
    }
}

extern "C" void kernel_launch(void* const* d_in, const int* in_sizes, int n_in,
                              void* d_out, int out_size, void* d_ws, size_t ws_size,
                              hipStream_t stream) {
    const float* x_q = (const float*)d_in[0];
    const float* x_k = (const float*)d_in[1];
    const float* x_v = (const float*)d_in[2];
    const int*   msk = (const int*)d_in[3];
    const float* q_w = (const float*)d_in[4];
    const float* q_b = (const float*)d_in[5];
    const float* k_w = (const float*)d_in[6];
    const float* k_b = (const float*)d_in[7];
    const float* v_w = (const float*)d_in[8];
    const float* v_b = (const float*)d_in[9];
    const float* o_w = (const float*)d_in[10];
    const float* o_b = (const float*)d_in[11];
    float* out = (float*)d_out;

    const size_t NEL = (size_t)BSZ * SEQ * DIMN;   // 4 Mi
    const size_t WEL = (size_t)DIMN * DIMN;        // 1 Mi
    // 32 MiB layout (same footprint as all passing rounds):
    //   Qp | Kp | VpT | Wq Wk Wv Wo ;  Cp aliases Qp (per-block read-before-write)
    ushort_t* Qp  = (ushort_t*)d_ws;
    ushort_t* Kp  = Qp + NEL;
    ushort_t* VpT = Kp + NEL;
    ushort_t* Wq  = VpT + NEL;
    ushort_t* Wk  = Wq + WEL;
    ushort_t* Wv  = Wk + WEL;
    ushort_t* Wo  = Wv + WEL;
    ushort_t* Cp  = Qp;

    cvt_w<<<dim3(WEL / 1024, 4), 256, 0, stream>>>(q_w, k_w, v_w, o_w, Wq, Wk, Wv, Wo);
    gemm_qkv<<<dim3(24, 32), 256, 0, stream>>>(x_q, x_k, x_v, Wq, Wk, Wv,
                                               q_b, k_b, v_b, Qp, Kp, VpT);
    attn_kernel<<<dim3(BSZ * NH, SEQ / 64), 256, 0, stream>>>(Qp, Kp, VpT, msk, Cp);
    gemm_o<<<dim3(16, 32), 256, 0, stream>>>(Cp, Wo, o_b, out);
}

// Round 8
// 307.623 us; speedup vs baseline: 1.0064x; 1.0064x over previous
//
#include <hip/hip_runtime.h>
#include <hip/hip_bf16.h>

#define BSZ 2
#define SEQ 2048
#define DIMN 1024
#define NH 16
#define DH 64
#define LOG2E 1.4426950408889634f

typedef unsigned short ushort_t;
typedef __attribute__((ext_vector_type(8))) short short8;
typedef __attribute__((ext_vector_type(4))) float float4v;

__device__ __forceinline__ ushort_t f2bf(float f) {
    union { float f; unsigned int u; } c; c.f = f;
    return (ushort_t)((c.u + 0x8000u) >> 16);
}
// packed 2xf32 -> 2xbf16 (v_cvt_pk_bf16_f32)
__device__ __forceinline__ unsigned int pkbf(float a, float b) {
    __hip_bfloat162 h = __float22bfloat162_rn(make_float2(a, b));
    unsigned int u; __builtin_memcpy(&u, &h, 4); return u;
}

// ---------------- weight pre-convert f32 -> bf16 (4 matrices, 1Mi each) -------------
__global__ __launch_bounds__(256) void cvt_w(
    const float* __restrict__ w0, const float* __restrict__ w1,
    const float* __restrict__ w2, const float* __restrict__ w3,
    ushort_t* __restrict__ o0, ushort_t* __restrict__ o1,
    ushort_t* __restrict__ o2, ushort_t* __restrict__ o3)
{
    const float* s; ushort_t* d;
    switch (blockIdx.y) {
        case 0: s = w0; d = o0; break;
        case 1: s = w1; d = o1; break;
        case 2: s = w2; d = o2; break;
        default: s = w3; d = o3; break;
    }
    int i = (blockIdx.x * 256 + threadIdx.x) * 4;
    float4v v = *(const float4v*)(s + i);
    uint2 o; o.x = pkbf(v[0], v[1]); o.y = pkbf(v[2], v[3]);
    *(uint2*)(d + i) = o;
}

// ---------------- QKV GEMM: 128x128, BK=32, reg-prefetch both, padded LDS -----------
// A f32 (pk-cvt during staging), W bf16. N axis 3072: Q(log2 scale) | K | V^T-out.
__global__ __launch_bounds__(256) void gemm_qkv(
    const float* __restrict__ xq, const float* __restrict__ xk, const float* __restrict__ xv,
    const ushort_t* __restrict__ Wq, const ushort_t* __restrict__ Wk, const ushort_t* __restrict__ Wv,
    const float* __restrict__ qb, const float* __restrict__ kb, const float* __restrict__ vb,
    ushort_t* __restrict__ Qp, ushort_t* __restrict__ Kp, ushort_t* __restrict__ VpT)
{
    __shared__ ushort_t As[128 * 40];   // stride 40 (20 dw): conflict-free frag reads
    __shared__ ushort_t Bs[128 * 40];
    const int tid  = threadIdx.x;
    const int lane = tid & 63;
    const int w    = tid >> 6;
    const int wm   = w >> 1, wn = w & 1;
    const int quad = lane >> 4;
    const int l16  = lane & 15;
    const int mBase = blockIdx.y * 128;
    const int nGlob = blockIdx.x * 128;
    const int z     = nGlob >> 10;
    const int nBase = nGlob & 1023;
    const float*    A    = (z == 0) ? xq : (z == 1) ? xk : xv;
    const ushort_t* W    = (z == 0) ? Wq : (z == 1) ? Wk : Wv;
    const float*    bias = (z == 0) ? qb : (z == 1) ? kb : vb;

    float4v acc[4][4];
    const float4v z4 = {0.f, 0.f, 0.f, 0.f};
#pragma unroll
    for (int i = 0; i < 4; ++i)
#pragma unroll
        for (int j = 0; j < 4; ++j) acc[i][j] = z4;

    for (int k0 = 0; k0 < 1024; k0 += 32) {
        // deep reg-prefetch (before barrier): A f32, W bf16
        float4v a0[2], a1[2];
        short8  wb[2];
#pragma unroll
        for (int it = 0; it < 2; ++it) {
            int c = it * 256 + tid, row = c >> 2, col = (c & 3) * 8;
            const float* g = A + (size_t)(mBase + row) * 1024 + k0 + col;
            a0[it] = *(const float4v*)g; a1[it] = *(const float4v*)(g + 4);
            wb[it] = *(const short8*)(W + (size_t)(nBase + row) * 1024 + k0 + col);
        }
        __syncthreads();   // prev-tile frag reads done
#pragma unroll
        for (int it = 0; it < 2; ++it) {
            int c = it * 256 + tid, row = c >> 2, col = (c & 3) * 8;
            uint4 ua;
            ua.x = pkbf(a0[it][0], a0[it][1]); ua.y = pkbf(a0[it][2], a0[it][3]);
            ua.z = pkbf(a1[it][0], a1[it][1]); ua.w = pkbf(a1[it][2], a1[it][3]);
            *(uint4*)&As[row * 40 + col] = ua;
            *(short8*)&Bs[row * 40 + col] = wb[it];
        }
        __syncthreads();   // staging visible

        short8 af[4], bf[4];
#pragma unroll
        for (int mt = 0; mt < 4; ++mt)
            af[mt] = *(const short8*)&As[(wm * 64 + mt * 16 + l16) * 40 + quad * 8];
#pragma unroll
        for (int nt = 0; nt < 4; ++nt)
            bf[nt] = *(const short8*)&Bs[(wn * 64 + nt * 16 + l16) * 40 + quad * 8];
#pragma unroll
        for (int mt = 0; mt < 4; ++mt)
#pragma unroll
            for (int nt = 0; nt < 4; ++nt)
                acc[mt][nt] = __builtin_amdgcn_mfma_f32_16x16x32_bf16(af[mt], bf[nt], acc[mt][nt], 0, 0, 0);
    }

    const float scale = (z == 0) ? 0.125f * LOG2E : 1.0f;
    if (z < 2) {
        ushort_t* C = (z == 0) ? Qp : Kp;
#pragma unroll
        for (int mt = 0; mt < 4; ++mt)
#pragma unroll
            for (int nt = 0; nt < 4; ++nt) {
                int colg = nBase + wn * 64 + nt * 16 + l16;
                float bv = bias[colg];
#pragma unroll
                for (int r = 0; r < 4; ++r) {
                    int rowg = mBase + wm * 64 + mt * 16 + quad * 4 + r;
                    C[(size_t)rowg * 1024 + colg] = f2bf((acc[mt][nt][r] + bv) * scale);
                }
            }
    } else {
        // V transposed out: VpT[((b*16+h)*64+d)*2048 + s], 4 consecutive s per lane
#pragma unroll
        for (int mt = 0; mt < 4; ++mt)
#pragma unroll
            for (int nt = 0; nt < 4; ++nt) {
                int n = nBase + wn * 64 + nt * 16 + l16;
                int hh = n >> 6, d = n & 63;
                float bv = bias[n];
                int rowg = mBase + wm * 64 + mt * 16 + quad * 4;
                int b = rowg >> 11, s = rowg & 2047;
                uint2 pk;
                pk.x = pkbf(acc[mt][nt][0] + bv, acc[mt][nt][1] + bv);
                pk.y = pkbf(acc[mt][nt][2] + bv, acc[mt][nt][3] + bv);
                *(uint2*)&VpT[(((size_t)(b * 16 + hh) * 64 + d) << 11) + s] = pk;
            }
    }
}

// ---------------- O GEMM: 128x64, BK=32, both bf16 reg-prefetch, padded LDS ---------
__global__ __launch_bounds__(256) void gemm_o(
    const ushort_t* __restrict__ A, const ushort_t* __restrict__ W,
    const float* __restrict__ bias, float* __restrict__ C)
{
    __shared__ ushort_t As[128 * 40];
    __shared__ ushort_t Bs[64 * 40];
    const int tid  = threadIdx.x;
    const int lane = tid & 63;
    const int w    = tid >> 6;
    const int wm   = w & 1, wn = w >> 1;
    const int quad = lane >> 4;
    const int l16  = lane & 15;
    const int mBase = blockIdx.y * 128;
    const int nBase = blockIdx.x * 64;

    float4v acc[4][2];
    const float4v z4 = {0.f, 0.f, 0.f, 0.f};
#pragma unroll
    for (int mt = 0; mt < 4; ++mt)
#pragma unroll
        for (int nt = 0; nt < 2; ++nt) acc[mt][nt] = z4;

    for (int k0 = 0; k0 < 1024; k0 += 32) {
        short8 ab[2], wb;
#pragma unroll
        for (int it = 0; it < 2; ++it) {
            int c = it * 256 + tid, row = c >> 2, col = (c & 3) * 8;
            ab[it] = *(const short8*)(A + (size_t)(mBase + row) * 1024 + k0 + col);
        }
        {
            int row = tid >> 2, col = (tid & 3) * 8;
            wb = *(const short8*)(W + (size_t)(nBase + row) * 1024 + k0 + col);
        }
        __syncthreads();
#pragma unroll
        for (int it = 0; it < 2; ++it) {
            int c = it * 256 + tid, row = c >> 2, col = (c & 3) * 8;
            *(short8*)&As[row * 40 + col] = ab[it];
        }
        {
            int row = tid >> 2, col = (tid & 3) * 8;
            *(short8*)&Bs[row * 40 + col] = wb;
        }
        __syncthreads();

        short8 af[4], bf[2];
#pragma unroll
        for (int mt = 0; mt < 4; ++mt)
            af[mt] = *(const short8*)&As[(wm * 64 + mt * 16 + l16) * 40 + quad * 8];
#pragma unroll
        for (int nt = 0; nt < 2; ++nt)
            bf[nt] = *(const short8*)&Bs[(wn * 32 + nt * 16 + l16) * 40 + quad * 8];
#pragma unroll
        for (int mt = 0; mt < 4; ++mt)
#pragma unroll
            for (int nt = 0; nt < 2; ++nt)
                acc[mt][nt] = __builtin_amdgcn_mfma_f32_16x16x32_bf16(af[mt], bf[nt], acc[mt][nt], 0, 0, 0);
    }

#pragma unroll
    for (int mt = 0; mt < 4; ++mt)
#pragma unroll
        for (int nt = 0; nt < 2; ++nt) {
            int colg = nBase + wn * 32 + nt * 16 + l16;
            float bv = bias[colg];
#pragma unroll
            for (int r = 0; r < 4; ++r) {
                int rowg = mBase + wm * 64 + mt * 16 + quad * 4 + r;
                C[(size_t)rowg * 1024 + colg] = acc[mt][nt][r] + bv;
            }
        }
}

// ---------------- fused flash attention, S^T form, Q-tile 128 -----------------------
// Each of 4 waves owns 32 q-rows (2 n-subtiles). K/V staging + ak/av frag reads are
// shared across both subtiles. Ps rows are wave-private (== the Q rows this wave
// loaded into bq), so no barrier between Ps write and PV reads.
__global__ __launch_bounds__(256) void attn_kernel(
    const ushort_t* __restrict__ Qp, const ushort_t* __restrict__ Kp,
    const ushort_t* __restrict__ VpT, const int* __restrict__ mask,
    ushort_t* __restrict__ Cp)
{
    __shared__ ushort_t QPs[128 * 72];  // Q staging, then per-wave Ps
    __shared__ ushort_t Ks[64 * 72];
    __shared__ ushort_t Vt[64 * 72];    // [dim][key]

    const int tid  = threadIdx.x;
    const int lane = tid & 63;
    const int w    = tid >> 6;
    const int quad = lane >> 4;
    const int l16  = lane & 15;
    const int b    = blockIdx.x >> 4;
    const int h    = blockIdx.x & 15;
    const int q0   = blockIdx.y * 128;

    // stage Q (128x64); hoist B-frags
    {
        short8 qreg[4];
#pragma unroll
        for (int it = 0; it < 4; ++it) {
            int c = it * 256 + tid, row = c >> 3, col = (c & 7) * 8;
            qreg[it] = *(const short8*)(Qp + (size_t)(b * SEQ + q0 + row) * DIMN + h * DH + col);
        }
#pragma unroll
        for (int it = 0; it < 4; ++it) {
            int c = it * 256 + tid, row = c >> 3, col = (c & 7) * 8;
            *(short8*)&QPs[row * 72 + col] = qreg[it];
        }
    }
    __syncthreads();
    short8 bq[2][2];   // [ks][qn]
#pragma unroll
    for (int ks = 0; ks < 2; ++ks)
#pragma unroll
        for (int qn = 0; qn < 2; ++qn)
            bq[ks][qn] = *(const short8*)&QPs[(w * 32 + qn * 16 + l16) * 72 + ks * 32 + quad * 8];

    const float4v z4 = {0.f, 0.f, 0.f, 0.f};
    float4v Oacc[2][4];   // [qn][vt]  O^T: [dim vt*16+quad*4+r][qrow l16]
#pragma unroll
    for (int qn = 0; qn < 2; ++qn)
#pragma unroll
        for (int vt = 0; vt < 4; ++vt) Oacc[qn][vt] = z4;
    float4v Lacc[2] = {z4, z4};
    float mrow[2] = {-3e38f, -3e38f};

    short8 ones;
#pragma unroll
    for (int j = 0; j < 8; ++j) ones[j] = (short)0x3F80;

    const ushort_t* Vbase = VpT + ((size_t)(b * 16 + h) * 64) * 2048;

    for (int kt0 = 0; kt0 < SEQ; kt0 += 64) {
        // reg-prefetch K tile, V^T tile, mask (loads overlap barrier-A wait)
        short8 kreg[2], vreg[2];
        int4 mv4[4];
#pragma unroll
        for (int it = 0; it < 2; ++it) {
            int c = it * 256 + tid, row = c >> 3, col = (c & 7) * 8;
            kreg[it] = *(const short8*)(Kp + (size_t)(b * SEQ + kt0 + row) * DIMN + h * DH + col);
            vreg[it] = *(const short8*)(Vbase + (size_t)row * 2048 + kt0 + col);
        }
#pragma unroll
        for (int kt = 0; kt < 4; ++kt)
            mv4[kt] = *(const int4*)(mask + b * SEQ + kt0 + kt * 16 + quad * 4);

        __syncthreads();   // prev-iter Ks/Vt reads complete
#pragma unroll
        for (int it = 0; it < 2; ++it) {
            int c = it * 256 + tid, row = c >> 3, col = (c & 7) * 8;
            *(short8*)&Ks[row * 72 + col] = kreg[it];
            *(short8*)&Vt[row * 72 + col] = vreg[it];
        }
        __syncthreads();   // staging visible

        // S^T = K.Q^T  (ak shared across both q-subtiles)
        float4v Sv[2][4];
#pragma unroll
        for (int qn = 0; qn < 2; ++qn)
#pragma unroll
            for (int kt = 0; kt < 4; ++kt) Sv[qn][kt] = z4;
#pragma unroll
        for (int ks = 0; ks < 2; ++ks)
#pragma unroll
            for (int kt = 0; kt < 4; ++kt) {
                short8 ak = *(const short8*)&Ks[(kt * 16 + l16) * 72 + ks * 32 + quad * 8];
#pragma unroll
                for (int qn = 0; qn < 2; ++qn)
                    Sv[qn][kt] = __builtin_amdgcn_mfma_f32_16x16x32_bf16(ak, bq[ks][qn], Sv[qn][kt], 0, 0, 0);
            }

        // additive mask (key = kt*16 + quad*4 + r)
#pragma unroll
        for (int kt = 0; kt < 4; ++kt) {
            int4 mv = mv4[kt];
#pragma unroll
            for (int r = 0; r < 4; ++r) {
                int m = (r == 0) ? mv.x : (r == 1) ? mv.y : (r == 2) ? mv.z : mv.w;
                float madd = (m == 0) ? -1e30f : 0.0f;
                Sv[0][kt][r] += madd;
                Sv[1][kt][r] += madd;
            }
        }

        // online softmax (base-2) per q-subtile
#pragma unroll
        for (int qn = 0; qn < 2; ++qn) {
            float mx = Sv[qn][0][0];
#pragma unroll
            for (int kt = 0; kt < 4; ++kt)
#pragma unroll
                for (int r = 0; r < 4; ++r) mx = fmaxf(mx, Sv[qn][kt][r]);
            mx = fmaxf(mx, __shfl_xor(mx, 16));
            mx = fmaxf(mx, __shfl_xor(mx, 32));
            float mn = fmaxf(mrow[qn], mx);
            float alpha = exp2f(mrow[qn] - mn);
            mrow[qn] = mn;
#pragma unroll
            for (int kt = 0; kt < 4; ++kt)
#pragma unroll
                for (int r = 0; r < 4; ++r) Sv[qn][kt][r] = exp2f(Sv[qn][kt][r] - mn);
#pragma unroll
            for (int vt = 0; vt < 4; ++vt) Oacc[qn][vt] *= alpha;
            Lacc[qn] *= alpha;

            // P -> Ps (wave-private rows), packed b64
#pragma unroll
            for (int kt = 0; kt < 4; ++kt) {
                uint2 pk;
                pk.x = pkbf(Sv[qn][kt][0], Sv[qn][kt][1]);
                pk.y = pkbf(Sv[qn][kt][2], Sv[qn][kt][3]);
                *(uint2*)&QPs[(w * 32 + qn * 16 + l16) * 72 + kt * 16 + quad * 4] = pk;
            }
        }

        // O^T += V^T.P^T ; L += 1.P^T  (av shared across q-subtiles)
#pragma unroll
        for (int ks = 0; ks < 2; ++ks) {
            short8 bp[2];
#pragma unroll
            for (int qn = 0; qn < 2; ++qn) {
                bp[qn] = *(const short8*)&QPs[(w * 32 + qn * 16 + l16) * 72 + ks * 32 + quad * 8];
                Lacc[qn] = __builtin_amdgcn_mfma_f32_16x16x32_bf16(ones, bp[qn], Lacc[qn], 0, 0, 0);
            }
#pragma unroll
            for (int vt = 0; vt < 4; ++vt) {
                short8 av = *(const short8*)&Vt[(vt * 16 + l16) * 72 + ks * 32 + quad * 8];
#pragma unroll
                for (int qn = 0; qn < 2; ++qn)
                    Oacc[qn][vt] = __builtin_amdgcn_mfma_f32_16x16x32_bf16(av, bp[qn], Oacc[qn][vt], 0, 0, 0);
            }
        }
    }

    // epilogue: O^T -> Cp[qrow][dim], packed 8B stores
#pragma unroll
    for (int qn = 0; qn < 2; ++qn) {
        float inv = 1.0f / Lacc[qn][0];
        int row = q0 + w * 32 + qn * 16 + l16;
#pragma unroll
        for (int vt = 0; vt < 4; ++vt) {
            uint2 pk;
            pk.x = pkbf(Oacc[qn][vt][0] * inv, Oacc[qn][vt][1] * inv);
            pk.y = pkbf(Oacc[qn][vt][2] * inv, Oacc[qn][vt][3] * inv);
            *(uint2*)&Cp[(size_t)(b * SEQ + row) * DIMN + h * DH + vt * 16 + quad * 4] = pk;
        }
    }
}

extern "C" void kernel_launch(void* const* d_in, const int* in_sizes, int n_in,
                              void* d_out, int out_size, void* d_ws, size_t ws_size,
                              hipStream_t stream) {
    const float* x_q = (const float*)d_in[0];
    const float* x_k = (const float*)d_in[1];
    const float* x_v = (const float*)d_in[2];
    const int*   msk = (const int*)d_in[3];
    const float* q_w = (const float*)d_in[4];
    const float* q_b = (const float*)d_in[5];
    const float* k_w = (const float*)d_in[6];
    const float* k_b = (const float*)d_in[7];
    const float* v_w = (const float*)d_in[8];
    const float* v_b = (const float*)d_in[9];
    const float* o_w = (const float*)d_in[10];
    const float* o_b = (const float*)d_in[11];
    float* out = (float*)d_out;

    const size_t NEL = (size_t)BSZ * SEQ * DIMN;   // 4 Mi
    const size_t WEL = (size_t)DIMN * DIMN;        // 1 Mi
    // 32 MiB layout: Qp | Kp | VpT | Wq Wk Wv Wo ; Cp aliases Qp (read-before-write)
    ushort_t* Qp  = (ushort_t*)d_ws;
    ushort_t* Kp  = Qp + NEL;
    ushort_t* VpT = Kp + NEL;
    ushort_t* Wq  = VpT + NEL;
    ushort_t* Wk  = Wq + WEL;
    ushort_t* Wv  = Wk + WEL;
    ushort_t* Wo  = Wv + WEL;
    ushort_t* Cp  = Qp;

    cvt_w<<<dim3(WEL / 1024, 4), 256, 0, stream>>>(q_w, k_w, v_w, o_w, Wq, Wk, Wv, Wo);
    gemm_qkv<<<dim3(24, 32), 256, 0, stream>>>(x_q, x_k, x_v, Wq, Wk, Wv,
                                               q_b, k_b, v_b, Qp, Kp, VpT);
    attn_kernel<<<dim3(BSZ * NH, SEQ / 128), 256, 0, stream>>>(Qp, Kp, VpT, msk, Cp);
    gemm_o<<<dim3(16, 32), 256, 0, stream>>>(Cp, Wo, o_b, out);
}

// Round 9
// 289.235 us; speedup vs baseline: 1.0704x; 1.0636x over previous
//
#include <hip/hip_runtime.h>
#include <hip/hip_bf16.h>

#define BSZ 2
#define SEQ 2048
#define DIMN 1024
#define NH 16
#define DH 64
#define LOG2E 1.4426950408889634f

typedef unsigned short ushort_t;
typedef __attribute__((ext_vector_type(8))) short short8;
typedef __attribute__((ext_vector_type(4))) float float4v;

__device__ __forceinline__ ushort_t f2bf(float f) {
    union { float f; unsigned int u; } c; c.f = f;
    return (ushort_t)((c.u + 0x8000u) >> 16);
}
// packed 2xf32 -> 2xbf16 (v_cvt_pk_bf16_f32)
__device__ __forceinline__ unsigned int pkbf(float a, float b) {
    __hip_bfloat162 h = __float22bfloat162_rn(make_float2(a, b));
    unsigned int u; __builtin_memcpy(&u, &h, 4); return u;
}

// ---------------- weight pre-convert f32 -> bf16 (4 matrices, 1Mi each) -------------
__global__ __launch_bounds__(256) void cvt_w(
    const float* __restrict__ w0, const float* __restrict__ w1,
    const float* __restrict__ w2, const float* __restrict__ w3,
    ushort_t* __restrict__ o0, ushort_t* __restrict__ o1,
    ushort_t* __restrict__ o2, ushort_t* __restrict__ o3)
{
    const float* s; ushort_t* d;
    switch (blockIdx.y) {
        case 0: s = w0; d = o0; break;
        case 1: s = w1; d = o1; break;
        case 2: s = w2; d = o2; break;
        default: s = w3; d = o3; break;
    }
    int i = (blockIdx.x * 256 + threadIdx.x) * 4;
    float4v v = *(const float4v*)(s + i);
    uint2 o; o.x = pkbf(v[0], v[1]); o.y = pkbf(v[2], v[3]);
    *(uint2*)(d + i) = o;
}

// ---------------- QKV GEMM: 128x128, BK=64 (half the barrier rounds) ----------------
// A f32 reg-prefetch + pk-cvt into As[128x72]; W bf16 reg-prefetch into Bs[128x72].
// Stride 72 shorts = 36 dw: 16-row frag reads are 2-way (free), rows 16B-aligned.
// N axis 3072: [0,1024) Q (log2 scale), [1024,2048) K, [2048,3072) V^T out.
__global__ __launch_bounds__(256) void gemm_qkv(
    const float* __restrict__ xq, const float* __restrict__ xk, const float* __restrict__ xv,
    const ushort_t* __restrict__ Wq, const ushort_t* __restrict__ Wk, const ushort_t* __restrict__ Wv,
    const float* __restrict__ qb, const float* __restrict__ kb, const float* __restrict__ vb,
    ushort_t* __restrict__ Qp, ushort_t* __restrict__ Kp, ushort_t* __restrict__ VpT)
{
    __shared__ ushort_t As[128 * 72];
    __shared__ ushort_t Bs[128 * 72];
    const int tid  = threadIdx.x;
    const int lane = tid & 63;
    const int w    = tid >> 6;
    const int wm   = w >> 1, wn = w & 1;
    const int quad = lane >> 4;
    const int l16  = lane & 15;
    const int mBase = blockIdx.y * 128;
    const int nGlob = blockIdx.x * 128;
    const int z     = nGlob >> 10;
    const int nBase = nGlob & 1023;
    const float*    A    = (z == 0) ? xq : (z == 1) ? xk : xv;
    const ushort_t* W    = (z == 0) ? Wq : (z == 1) ? Wk : Wv;
    const float*    bias = (z == 0) ? qb : (z == 1) ? kb : vb;

    float4v acc[4][4];
    const float4v z4 = {0.f, 0.f, 0.f, 0.f};
#pragma unroll
    for (int i = 0; i < 4; ++i)
#pragma unroll
        for (int j = 0; j < 4; ++j) acc[i][j] = z4;

    for (int k0 = 0; k0 < 1024; k0 += 64) {
        // reg-prefetch one 128x64 tile of A (f32) and W (bf16) before the barrier
        float4v a[4][2];
        short8  wb[4];
#pragma unroll
        for (int it = 0; it < 4; ++it) {
            int c = it * 256 + tid, row = c >> 3, col = (c & 7) * 8;
            const float* g = A + (size_t)(mBase + row) * 1024 + k0 + col;
            a[it][0] = *(const float4v*)g;
            a[it][1] = *(const float4v*)(g + 4);
            wb[it] = *(const short8*)(W + (size_t)(nBase + row) * 1024 + k0 + col);
        }
        __syncthreads();   // prev-tile frag reads done
#pragma unroll
        for (int it = 0; it < 4; ++it) {
            int c = it * 256 + tid, row = c >> 3, col = (c & 7) * 8;
            uint4 ua;
            ua.x = pkbf(a[it][0][0], a[it][0][1]); ua.y = pkbf(a[it][0][2], a[it][0][3]);
            ua.z = pkbf(a[it][1][0], a[it][1][1]); ua.w = pkbf(a[it][1][2], a[it][1][3]);
            *(uint4*)&As[row * 72 + col] = ua;
            *(short8*)&Bs[row * 72 + col] = wb[it];
        }
        __syncthreads();   // staging visible

#pragma unroll
        for (int ksub = 0; ksub < 2; ++ksub) {
            short8 af[4], bf[4];
#pragma unroll
            for (int mt = 0; mt < 4; ++mt)
                af[mt] = *(const short8*)&As[(wm * 64 + mt * 16 + l16) * 72 + ksub * 32 + quad * 8];
#pragma unroll
            for (int nt = 0; nt < 4; ++nt)
                bf[nt] = *(const short8*)&Bs[(wn * 64 + nt * 16 + l16) * 72 + ksub * 32 + quad * 8];
#pragma unroll
            for (int mt = 0; mt < 4; ++mt)
#pragma unroll
                for (int nt = 0; nt < 4; ++nt)
                    acc[mt][nt] = __builtin_amdgcn_mfma_f32_16x16x32_bf16(af[mt], bf[nt], acc[mt][nt], 0, 0, 0);
        }
    }

    const float scale = (z == 0) ? 0.125f * LOG2E : 1.0f;
    if (z < 2) {
        ushort_t* C = (z == 0) ? Qp : Kp;
#pragma unroll
        for (int mt = 0; mt < 4; ++mt)
#pragma unroll
            for (int nt = 0; nt < 4; ++nt) {
                int colg = nBase + wn * 64 + nt * 16 + l16;
                float bv = bias[colg];
#pragma unroll
                for (int r = 0; r < 4; ++r) {
                    int rowg = mBase + wm * 64 + mt * 16 + quad * 4 + r;
                    C[(size_t)rowg * 1024 + colg] = f2bf((acc[mt][nt][r] + bv) * scale);
                }
            }
    } else {
        // V transposed out: VpT[((b*16+h)*64+d)*2048 + s], 4 consecutive s per lane
#pragma unroll
        for (int mt = 0; mt < 4; ++mt)
#pragma unroll
            for (int nt = 0; nt < 4; ++nt) {
                int n = nBase + wn * 64 + nt * 16 + l16;
                int hh = n >> 6, d = n & 63;
                float bv = bias[n];
                int rowg = mBase + wm * 64 + mt * 16 + quad * 4;
                int b = rowg >> 11, s = rowg & 2047;
                uint2 pk;
                pk.x = pkbf(acc[mt][nt][0] + bv, acc[mt][nt][1] + bv);
                pk.y = pkbf(acc[mt][nt][2] + bv, acc[mt][nt][3] + bv);
                *(uint2*)&VpT[(((size_t)(b * 16 + hh) * 64 + d) << 11) + s] = pk;
            }
    }
}

// ---------------- O GEMM: 128x64, BK=32, both bf16 reg-prefetch, padded LDS ---------
__global__ __launch_bounds__(256) void gemm_o(
    const ushort_t* __restrict__ A, const ushort_t* __restrict__ W,
    const float* __restrict__ bias, float* __restrict__ C)
{
    __shared__ ushort_t As[128 * 40];
    __shared__ ushort_t Bs[64 * 40];
    const int tid  = threadIdx.x;
    const int lane = tid & 63;
    const int w    = tid >> 6;
    const int wm   = w & 1, wn = w >> 1;
    const int quad = lane >> 4;
    const int l16  = lane & 15;
    const int mBase = blockIdx.y * 128;
    const int nBase = blockIdx.x * 64;

    float4v acc[4][2];
    const float4v z4 = {0.f, 0.f, 0.f, 0.f};
#pragma unroll
    for (int mt = 0; mt < 4; ++mt)
#pragma unroll
        for (int nt = 0; nt < 2; ++nt) acc[mt][nt] = z4;

    for (int k0 = 0; k0 < 1024; k0 += 32) {
        short8 ab[2], wb;
#pragma unroll
        for (int it = 0; it < 2; ++it) {
            int c = it * 256 + tid, row = c >> 2, col = (c & 3) * 8;
            ab[it] = *(const short8*)(A + (size_t)(mBase + row) * 1024 + k0 + col);
        }
        {
            int row = tid >> 2, col = (tid & 3) * 8;
            wb = *(const short8*)(W + (size_t)(nBase + row) * 1024 + k0 + col);
        }
        __syncthreads();
#pragma unroll
        for (int it = 0; it < 2; ++it) {
            int c = it * 256 + tid, row = c >> 2, col = (c & 3) * 8;
            *(short8*)&As[row * 40 + col] = ab[it];
        }
        {
            int row = tid >> 2, col = (tid & 3) * 8;
            *(short8*)&Bs[row * 40 + col] = wb;
        }
        __syncthreads();

        short8 af[4], bf[2];
#pragma unroll
        for (int mt = 0; mt < 4; ++mt)
            af[mt] = *(const short8*)&As[(wm * 64 + mt * 16 + l16) * 40 + quad * 8];
#pragma unroll
        for (int nt = 0; nt < 2; ++nt)
            bf[nt] = *(const short8*)&Bs[(wn * 32 + nt * 16 + l16) * 40 + quad * 8];
#pragma unroll
        for (int mt = 0; mt < 4; ++mt)
#pragma unroll
            for (int nt = 0; nt < 2; ++nt)
                acc[mt][nt] = __builtin_amdgcn_mfma_f32_16x16x32_bf16(af[mt], bf[nt], acc[mt][nt], 0, 0, 0);
    }

#pragma unroll
    for (int mt = 0; mt < 4; ++mt)
#pragma unroll
        for (int nt = 0; nt < 2; ++nt) {
            int colg = nBase + wn * 32 + nt * 16 + l16;
            float bv = bias[colg];
#pragma unroll
            for (int r = 0; r < 4; ++r) {
                int rowg = mBase + wm * 64 + mt * 16 + quad * 4 + r;
                C[(size_t)rowg * 1024 + colg] = acc[mt][nt][r] + bv;
            }
        }
}

// ---------------- fused flash attention, S^T form, Q-tile 64 (measured best) --------
__global__ __launch_bounds__(256) void attn_kernel(
    const ushort_t* __restrict__ Qp, const ushort_t* __restrict__ Kp,
    const ushort_t* __restrict__ VpT, const int* __restrict__ mask,
    ushort_t* __restrict__ Cp)
{
    __shared__ ushort_t QPs[64 * 72];  // Q staging, then reused as Ps
    __shared__ ushort_t Ks[64 * 72];
    __shared__ ushort_t Vt[64 * 72];   // [dim][key]

    const int tid  = threadIdx.x;
    const int lane = tid & 63;
    const int w    = tid >> 6;
    const int quad = lane >> 4;
    const int l16  = lane & 15;
    const int b    = blockIdx.x >> 4;
    const int h    = blockIdx.x & 15;
    const int q0   = blockIdx.y * 64;

    // stage Q (64x64), then hoist B-frags (Q region recycled as Ps)
    {
        short8 qreg[2];
#pragma unroll
        for (int it = 0; it < 2; ++it) {
            int c = it * 256 + tid, row = c >> 3, col = (c & 7) * 8;
            qreg[it] = *(const short8*)(Qp + (size_t)(b * SEQ + q0 + row) * DIMN + h * DH + col);
        }
#pragma unroll
        for (int it = 0; it < 2; ++it) {
            int c = it * 256 + tid, row = c >> 3, col = (c & 7) * 8;
            *(short8*)&QPs[row * 72 + col] = qreg[it];
        }
    }
    __syncthreads();
    short8 bq[2];
#pragma unroll
    for (int ks = 0; ks < 2; ++ks)
        bq[ks] = *(const short8*)&QPs[(w * 16 + l16) * 72 + ks * 32 + quad * 8];

    const float4v z4 = {0.f, 0.f, 0.f, 0.f};
    float4v Oacc[4];   // O^T: [dim vt*16+quad*4+r][qrow l16]
#pragma unroll
    for (int vt = 0; vt < 4; ++vt) Oacc[vt] = z4;
    float4v Lacc = z4;
    float mrow = -3e38f;

    short8 ones;
#pragma unroll
    for (int j = 0; j < 8; ++j) ones[j] = (short)0x3F80;

    const ushort_t* Vbase = VpT + ((size_t)(b * 16 + h) * 64) * 2048;

    for (int kt0 = 0; kt0 < SEQ; kt0 += 64) {
        // reg-prefetch K tile, V^T tile, mask (issued before barrier wait)
        short8 kreg[2], vreg[2];
        int4 mv4[4];
#pragma unroll
        for (int it = 0; it < 2; ++it) {
            int c = it * 256 + tid, row = c >> 3, col = (c & 7) * 8;
            kreg[it] = *(const short8*)(Kp + (size_t)(b * SEQ + kt0 + row) * DIMN + h * DH + col);
            vreg[it] = *(const short8*)(Vbase + (size_t)row * 2048 + kt0 + col);
        }
#pragma unroll
        for (int kt = 0; kt < 4; ++kt)
            mv4[kt] = *(const int4*)(mask + b * SEQ + kt0 + kt * 16 + quad * 4);

        __syncthreads();   // prev-iter LDS reads complete
#pragma unroll
        for (int it = 0; it < 2; ++it) {
            int c = it * 256 + tid, row = c >> 3, col = (c & 7) * 8;
            *(short8*)&Ks[row * 72 + col] = kreg[it];
            *(short8*)&Vt[row * 72 + col] = vreg[it];
        }
        __syncthreads();   // staging visible

        // S^T = K.Q^T (log2 domain; Q pre-scaled)
        float4v Sv[4];
#pragma unroll
        for (int kt = 0; kt < 4; ++kt) Sv[kt] = z4;
#pragma unroll
        for (int ks = 0; ks < 2; ++ks)
#pragma unroll
            for (int kt = 0; kt < 4; ++kt) {
                short8 ak = *(const short8*)&Ks[(kt * 16 + l16) * 72 + ks * 32 + quad * 8];
                Sv[kt] = __builtin_amdgcn_mfma_f32_16x16x32_bf16(ak, bq[ks], Sv[kt], 0, 0, 0);
            }

        // additive mask (key = kt*16 + quad*4 + r)
#pragma unroll
        for (int kt = 0; kt < 4; ++kt) {
            int4 mv = mv4[kt];
#pragma unroll
            for (int r = 0; r < 4; ++r) {
                int m = (r == 0) ? mv.x : (r == 1) ? mv.y : (r == 2) ? mv.z : mv.w;
                Sv[kt][r] += (m == 0) ? -1e30f : 0.0f;
            }
        }

        // online softmax (base-2), all 16 scores belong to qrow l16
        float mx = Sv[0][0];
#pragma unroll
        for (int kt = 0; kt < 4; ++kt)
#pragma unroll
            for (int r = 0; r < 4; ++r) mx = fmaxf(mx, Sv[kt][r]);
        mx = fmaxf(mx, __shfl_xor(mx, 16));
        mx = fmaxf(mx, __shfl_xor(mx, 32));
        float mn = fmaxf(mrow, mx);
        float alpha = exp2f(mrow - mn);
        mrow = mn;
#pragma unroll
        for (int kt = 0; kt < 4; ++kt)
#pragma unroll
            for (int r = 0; r < 4; ++r) Sv[kt][r] = exp2f(Sv[kt][r] - mn);
#pragma unroll
        for (int vt = 0; vt < 4; ++vt) Oacc[vt] *= alpha;
        Lacc *= alpha;

        // P -> Ps[qrow][key] packed b64 (wave-private rows, lgkmcnt-ordered)
#pragma unroll
        for (int kt = 0; kt < 4; ++kt) {
            uint2 pk;
            pk.x = pkbf(Sv[kt][0], Sv[kt][1]);
            pk.y = pkbf(Sv[kt][2], Sv[kt][3]);
            *(uint2*)&QPs[(w * 16 + l16) * 72 + kt * 16 + quad * 4] = pk;
        }

        // O^T += V^T.P^T ; L += 1.P^T
#pragma unroll
        for (int ks = 0; ks < 2; ++ks) {
            short8 bp = *(const short8*)&QPs[(w * 16 + l16) * 72 + ks * 32 + quad * 8];
            Lacc = __builtin_amdgcn_mfma_f32_16x16x32_bf16(ones, bp, Lacc, 0, 0, 0);
#pragma unroll
            for (int vt = 0; vt < 4; ++vt) {
                short8 av = *(const short8*)&Vt[(vt * 16 + l16) * 72 + ks * 32 + quad * 8];
                Oacc[vt] = __builtin_amdgcn_mfma_f32_16x16x32_bf16(av, bp, Oacc[vt], 0, 0, 0);
            }
        }
    }

    // epilogue: O^T -> Cp[qrow][dim], packed 8B stores
    float inv = 1.0f / Lacc[0];
    int row = q0 + w * 16 + l16;
#pragma unroll
    for (int vt = 0; vt < 4; ++vt) {
        uint2 pk;
        pk.x = pkbf(Oacc[vt][0] * inv, Oacc[vt][1] * inv);
        pk.y = pkbf(Oacc[vt][2] * inv, Oacc[vt][3] * inv);
        *(uint2*)&Cp[(size_t)(b * SEQ + row) * DIMN + h * DH + vt * 16 + quad * 4] = pk;
    }
}

extern "C" void kernel_launch(void* const* d_in, const int* in_sizes, int n_in,
                              void* d_out, int out_size, void* d_ws, size_t ws_size,
                              hipStream_t stream) {
    const float* x_q = (const float*)d_in[0];
    const float* x_k = (const float*)d_in[1];
    const float* x_v = (const float*)d_in[2];
    const int*   msk = (const int*)d_in[3];
    const float* q_w = (const float*)d_in[4];
    const float* q_b = (const float*)d_in[5];
    const float* k_w = (const float*)d_in[6];
    const float* k_b = (const float*)d_in[7];
    const float* v_w = (const float*)d_in[8];
    const float* v_b = (const float*)d_in[9];
    const float* o_w = (const float*)d_in[10];
    const float* o_b = (const float*)d_in[11];
    float* out = (float*)d_out;

    const size_t NEL = (size_t)BSZ * SEQ * DIMN;   // 4 Mi
    const size_t WEL = (size_t)DIMN * DIMN;        // 1 Mi
    // 32 MiB layout: Qp | Kp | VpT | Wq Wk Wv Wo ; Cp aliases Qp (read-before-write)
    ushort_t* Qp  = (ushort_t*)d_ws;
    ushort_t* Kp  = Qp + NEL;
    ushort_t* VpT = Kp + NEL;
    ushort_t* Wq  = VpT + NEL;
    ushort_t* Wk  = Wq + WEL;
    ushort_t* Wv  = Wk + WEL;
    ushort_t* Wo  = Wv + WEL;
    ushort_t* Cp  = Qp;

    cvt_w<<<dim3(WEL / 1024, 4), 256, 0, stream>>>(q_w, k_w, v_w, o_w, Wq, Wk, Wv, Wo);
    gemm_qkv<<<dim3(24, 32), 256, 0, stream>>>(x_q, x_k, x_v, Wq, Wk, Wv,
                                               q_b, k_b, v_b, Qp, Kp, VpT);
    attn_kernel<<<dim3(BSZ * NH, SEQ / 64), 256, 0, stream>>>(Qp, Kp, VpT, msk, Cp);
    gemm_o<<<dim3(16, 32), 256, 0, stream>>>(Cp, Wo, o_b, out);
}

// Round 10
// 267.058 us; speedup vs baseline: 1.1593x; 1.0830x over previous
//
#include <hip/hip_runtime.h>
#include <hip/hip_bf16.h>

#define BSZ 2
#define SEQ 2048
#define DIMN 1024
#define NH 16
#define DH 64
#define LOG2E 1.4426950408889634f

typedef unsigned short ushort_t;
typedef __attribute__((ext_vector_type(8))) short short8;
typedef __attribute__((ext_vector_type(4))) float float4v;

__device__ __forceinline__ ushort_t f2bf(float f) {
    union { float f; unsigned int u; } c; c.f = f;
    return (ushort_t)((c.u + 0x8000u) >> 16);
}
// packed 2xf32 -> 2xbf16 (v_cvt_pk_bf16_f32)
__device__ __forceinline__ unsigned int pkbf(float a, float b) {
    __hip_bfloat162 h = __float22bfloat162_rn(make_float2(a, b));
    unsigned int u; __builtin_memcpy(&u, &h, 4); return u;
}

// ---------------- weight pre-convert f32 -> bf16 (4 matrices, 1Mi each) -------------
__global__ __launch_bounds__(256) void cvt_w(
    const float* __restrict__ w0, const float* __restrict__ w1,
    const float* __restrict__ w2, const float* __restrict__ w3,
    ushort_t* __restrict__ o0, ushort_t* __restrict__ o1,
    ushort_t* __restrict__ o2, ushort_t* __restrict__ o3)
{
    const float* s; ushort_t* d;
    switch (blockIdx.y) {
        case 0: s = w0; d = o0; break;
        case 1: s = w1; d = o1; break;
        case 2: s = w2; d = o2; break;
        default: s = w3; d = o3; break;
    }
    int i = (blockIdx.x * 256 + threadIdx.x) * 4;
    float4v v = *(const float4v*)(s + i);
    uint2 o; o.x = pkbf(v[0], v[1]); o.y = pkbf(v[2], v[3]);
    *(uint2*)(d + i) = o;
}

// ---------------- QKV GEMM: 128x128, BK=64 (unchanged from R9 — measured win) -------
__global__ __launch_bounds__(256) void gemm_qkv(
    const float* __restrict__ xq, const float* __restrict__ xk, const float* __restrict__ xv,
    const ushort_t* __restrict__ Wq, const ushort_t* __restrict__ Wk, const ushort_t* __restrict__ Wv,
    const float* __restrict__ qb, const float* __restrict__ kb, const float* __restrict__ vb,
    ushort_t* __restrict__ Qp, ushort_t* __restrict__ Kp, ushort_t* __restrict__ VpT)
{
    __shared__ ushort_t As[128 * 72];
    __shared__ ushort_t Bs[128 * 72];
    const int tid  = threadIdx.x;
    const int lane = tid & 63;
    const int w    = tid >> 6;
    const int wm   = w >> 1, wn = w & 1;
    const int quad = lane >> 4;
    const int l16  = lane & 15;
    const int mBase = blockIdx.y * 128;
    const int nGlob = blockIdx.x * 128;
    const int z     = nGlob >> 10;
    const int nBase = nGlob & 1023;
    const float*    A    = (z == 0) ? xq : (z == 1) ? xk : xv;
    const ushort_t* W    = (z == 0) ? Wq : (z == 1) ? Wk : Wv;
    const float*    bias = (z == 0) ? qb : (z == 1) ? kb : vb;

    float4v acc[4][4];
    const float4v z4 = {0.f, 0.f, 0.f, 0.f};
#pragma unroll
    for (int i = 0; i < 4; ++i)
#pragma unroll
        for (int j = 0; j < 4; ++j) acc[i][j] = z4;

    for (int k0 = 0; k0 < 1024; k0 += 64) {
        float4v a[4][2];
        short8  wb[4];
#pragma unroll
        for (int it = 0; it < 4; ++it) {
            int c = it * 256 + tid, row = c >> 3, col = (c & 7) * 8;
            const float* g = A + (size_t)(mBase + row) * 1024 + k0 + col;
            a[it][0] = *(const float4v*)g;
            a[it][1] = *(const float4v*)(g + 4);
            wb[it] = *(const short8*)(W + (size_t)(nBase + row) * 1024 + k0 + col);
        }
        __syncthreads();
#pragma unroll
        for (int it = 0; it < 4; ++it) {
            int c = it * 256 + tid, row = c >> 3, col = (c & 7) * 8;
            uint4 ua;
            ua.x = pkbf(a[it][0][0], a[it][0][1]); ua.y = pkbf(a[it][0][2], a[it][0][3]);
            ua.z = pkbf(a[it][1][0], a[it][1][1]); ua.w = pkbf(a[it][1][2], a[it][1][3]);
            *(uint4*)&As[row * 72 + col] = ua;
            *(short8*)&Bs[row * 72 + col] = wb[it];
        }
        __syncthreads();

#pragma unroll
        for (int ksub = 0; ksub < 2; ++ksub) {
            short8 af[4], bf[4];
#pragma unroll
            for (int mt = 0; mt < 4; ++mt)
                af[mt] = *(const short8*)&As[(wm * 64 + mt * 16 + l16) * 72 + ksub * 32 + quad * 8];
#pragma unroll
            for (int nt = 0; nt < 4; ++nt)
                bf[nt] = *(const short8*)&Bs[(wn * 64 + nt * 16 + l16) * 72 + ksub * 32 + quad * 8];
#pragma unroll
            for (int mt = 0; mt < 4; ++mt)
#pragma unroll
                for (int nt = 0; nt < 4; ++nt)
                    acc[mt][nt] = __builtin_amdgcn_mfma_f32_16x16x32_bf16(af[mt], bf[nt], acc[mt][nt], 0, 0, 0);
        }
    }

    const float scale = (z == 0) ? 0.125f * LOG2E : 1.0f;
    if (z < 2) {
        ushort_t* C = (z == 0) ? Qp : Kp;
#pragma unroll
        for (int mt = 0; mt < 4; ++mt)
#pragma unroll
            for (int nt = 0; nt < 4; ++nt) {
                int colg = nBase + wn * 64 + nt * 16 + l16;
                float bv = bias[colg];
#pragma unroll
                for (int r = 0; r < 4; ++r) {
                    int rowg = mBase + wm * 64 + mt * 16 + quad * 4 + r;
                    C[(size_t)rowg * 1024 + colg] = f2bf((acc[mt][nt][r] + bv) * scale);
                }
            }
    } else {
#pragma unroll
        for (int mt = 0; mt < 4; ++mt)
#pragma unroll
            for (int nt = 0; nt < 4; ++nt) {
                int n = nBase + wn * 64 + nt * 16 + l16;
                int hh = n >> 6, d = n & 63;
                float bv = bias[n];
                int rowg = mBase + wm * 64 + mt * 16 + quad * 4;
                int b = rowg >> 11, s = rowg & 2047;
                uint2 pk;
                pk.x = pkbf(acc[mt][nt][0] + bv, acc[mt][nt][1] + bv);
                pk.y = pkbf(acc[mt][nt][2] + bv, acc[mt][nt][3] + bv);
                *(uint2*)&VpT[(((size_t)(b * 16 + hh) * 64 + d) << 11) + s] = pk;
            }
    }
}

// ---------------- O GEMM: 128x64, BK=64, both bf16 reg-prefetch ---------------------
__global__ __launch_bounds__(256) void gemm_o(
    const ushort_t* __restrict__ A, const ushort_t* __restrict__ W,
    const float* __restrict__ bias, float* __restrict__ C)
{
    __shared__ ushort_t As[128 * 72];
    __shared__ ushort_t Bs[64 * 72];
    const int tid  = threadIdx.x;
    const int lane = tid & 63;
    const int w    = tid >> 6;
    const int wm   = w & 1, wn = w >> 1;
    const int quad = lane >> 4;
    const int l16  = lane & 15;
    const int mBase = blockIdx.y * 128;
    const int nBase = blockIdx.x * 64;

    float4v acc[4][2];
    const float4v z4 = {0.f, 0.f, 0.f, 0.f};
#pragma unroll
    for (int mt = 0; mt < 4; ++mt)
#pragma unroll
        for (int nt = 0; nt < 2; ++nt) acc[mt][nt] = z4;

    for (int k0 = 0; k0 < 1024; k0 += 64) {
        short8 ab[4], wb[2];
#pragma unroll
        for (int it = 0; it < 4; ++it) {
            int c = it * 256 + tid, row = c >> 3, col = (c & 7) * 8;
            ab[it] = *(const short8*)(A + (size_t)(mBase + row) * 1024 + k0 + col);
        }
#pragma unroll
        for (int it = 0; it < 2; ++it) {
            int c = it * 256 + tid, row = c >> 3, col = (c & 7) * 8;
            wb[it] = *(const short8*)(W + (size_t)(nBase + row) * 1024 + k0 + col);
        }
        __syncthreads();
#pragma unroll
        for (int it = 0; it < 4; ++it) {
            int c = it * 256 + tid, row = c >> 3, col = (c & 7) * 8;
            *(short8*)&As[row * 72 + col] = ab[it];
        }
#pragma unroll
        for (int it = 0; it < 2; ++it) {
            int c = it * 256 + tid, row = c >> 3, col = (c & 7) * 8;
            *(short8*)&Bs[row * 72 + col] = wb[it];
        }
        __syncthreads();

#pragma unroll
        for (int ksub = 0; ksub < 2; ++ksub) {
            short8 af[4], bf[2];
#pragma unroll
            for (int mt = 0; mt < 4; ++mt)
                af[mt] = *(const short8*)&As[(wm * 64 + mt * 16 + l16) * 72 + ksub * 32 + quad * 8];
#pragma unroll
            for (int nt = 0; nt < 2; ++nt)
                bf[nt] = *(const short8*)&Bs[(wn * 32 + nt * 16 + l16) * 72 + ksub * 32 + quad * 8];
#pragma unroll
            for (int mt = 0; mt < 4; ++mt)
#pragma unroll
                for (int nt = 0; nt < 2; ++nt)
                    acc[mt][nt] = __builtin_amdgcn_mfma_f32_16x16x32_bf16(af[mt], bf[nt], acc[mt][nt], 0, 0, 0);
        }
    }

#pragma unroll
    for (int mt = 0; mt < 4; ++mt)
#pragma unroll
        for (int nt = 0; nt < 2; ++nt) {
            int colg = nBase + wn * 32 + nt * 16 + l16;
            float bv = bias[colg];
#pragma unroll
            for (int r = 0; r < 4; ++r) {
                int rowg = mBase + wm * 64 + mt * 16 + quad * 4 + r;
                C[(size_t)rowg * 1024 + colg] = acc[mt][nt][r] + bv;
            }
        }
}

// ---------------- fused flash attention: S^T form, Q-tile 128, 8 waves --------------
// Per-wave state identical to the Q64/4-wave version (VGPR ~64); K/V staging per
// thread halves (1 K + 1 V b128 instead of 2+2) and K/V global traffic halves.
__global__ __launch_bounds__(512) void attn_kernel(
    const ushort_t* __restrict__ Qp, const ushort_t* __restrict__ Kp,
    const ushort_t* __restrict__ VpT, const int* __restrict__ mask,
    ushort_t* __restrict__ Cp)
{
    __shared__ ushort_t QPs[128 * 72];  // Q staging, then per-wave Ps rows
    __shared__ ushort_t Ks[64 * 72];
    __shared__ ushort_t Vt[64 * 72];    // [dim][key]

    const int tid  = threadIdx.x;
    const int lane = tid & 63;
    const int w    = tid >> 6;          // 0..7
    const int quad = lane >> 4;
    const int l16  = lane & 15;
    const int b    = blockIdx.x >> 4;
    const int h    = blockIdx.x & 15;
    const int q0   = blockIdx.y * 128;

    // stage Q (128x64): 1024 chunks, 512 threads, 2 iters
    {
        short8 qreg[2];
#pragma unroll
        for (int it = 0; it < 2; ++it) {
            int c = it * 512 + tid, row = c >> 3, col = (c & 7) * 8;
            qreg[it] = *(const short8*)(Qp + (size_t)(b * SEQ + q0 + row) * DIMN + h * DH + col);
        }
#pragma unroll
        for (int it = 0; it < 2; ++it) {
            int c = it * 512 + tid, row = c >> 3, col = (c & 7) * 8;
            *(short8*)&QPs[row * 72 + col] = qreg[it];
        }
    }
    __syncthreads();
    short8 bq[2];
#pragma unroll
    for (int ks = 0; ks < 2; ++ks)
        bq[ks] = *(const short8*)&QPs[(w * 16 + l16) * 72 + ks * 32 + quad * 8];

    const float4v z4 = {0.f, 0.f, 0.f, 0.f};
    float4v Oacc[4];   // O^T: [dim vt*16+quad*4+r][qrow l16]
#pragma unroll
    for (int vt = 0; vt < 4; ++vt) Oacc[vt] = z4;
    float4v Lacc = z4;
    float mrow = -3e38f;

    short8 ones;
#pragma unroll
    for (int j = 0; j < 8; ++j) ones[j] = (short)0x3F80;

    const ushort_t* Vbase = VpT + ((size_t)(b * 16 + h) * 64) * 2048;
    const int srow = tid >> 3, scol = (tid & 7) * 8;   // staging coords (512 thr = 1 tile)

    for (int kt0 = 0; kt0 < SEQ; kt0 += 64) {
        // reg-prefetch K tile + V^T tile (1 b128 each) + mask
        short8 kreg = *(const short8*)(Kp + (size_t)(b * SEQ + kt0 + srow) * DIMN + h * DH + scol);
        short8 vreg = *(const short8*)(Vbase + (size_t)srow * 2048 + kt0 + scol);
        int4 mv4[4];
#pragma unroll
        for (int kt = 0; kt < 4; ++kt)
            mv4[kt] = *(const int4*)(mask + b * SEQ + kt0 + kt * 16 + quad * 4);

        __syncthreads();   // prev-iter LDS reads complete
        *(short8*)&Ks[srow * 72 + scol] = kreg;
        *(short8*)&Vt[srow * 72 + scol] = vreg;
        __syncthreads();   // staging visible

        // S^T = K.Q^T (log2 domain; Q pre-scaled)
        float4v Sv[4];
#pragma unroll
        for (int kt = 0; kt < 4; ++kt) Sv[kt] = z4;
#pragma unroll
        for (int ks = 0; ks < 2; ++ks)
#pragma unroll
            for (int kt = 0; kt < 4; ++kt) {
                short8 ak = *(const short8*)&Ks[(kt * 16 + l16) * 72 + ks * 32 + quad * 8];
                Sv[kt] = __builtin_amdgcn_mfma_f32_16x16x32_bf16(ak, bq[ks], Sv[kt], 0, 0, 0);
            }

        // additive mask (key = kt*16 + quad*4 + r), fast-path when tile unmasked
        int allm = (mv4[0].x & mv4[0].y & mv4[0].z & mv4[0].w) &
                   (mv4[1].x & mv4[1].y & mv4[1].z & mv4[1].w) &
                   (mv4[2].x & mv4[2].y & mv4[2].z & mv4[2].w) &
                   (mv4[3].x & mv4[3].y & mv4[3].z & mv4[3].w);
        if (__any(allm == 0)) {
#pragma unroll
            for (int kt = 0; kt < 4; ++kt) {
                int4 mv = mv4[kt];
#pragma unroll
                for (int r = 0; r < 4; ++r) {
                    int m = (r == 0) ? mv.x : (r == 1) ? mv.y : (r == 2) ? mv.z : mv.w;
                    Sv[kt][r] += (m == 0) ? -1e30f : 0.0f;
                }
            }
        }

        // online softmax (base-2), all 16 scores belong to qrow l16
        float mx = Sv[0][0];
#pragma unroll
        for (int kt = 0; kt < 4; ++kt)
#pragma unroll
            for (int r = 0; r < 4; ++r) mx = fmaxf(mx, Sv[kt][r]);
        mx = fmaxf(mx, __shfl_xor(mx, 16));
        mx = fmaxf(mx, __shfl_xor(mx, 32));
        float mn = fmaxf(mrow, mx);
        float alpha = exp2f(mrow - mn);
        mrow = mn;
#pragma unroll
        for (int kt = 0; kt < 4; ++kt)
#pragma unroll
            for (int r = 0; r < 4; ++r) Sv[kt][r] = exp2f(Sv[kt][r] - mn);
#pragma unroll
        for (int vt = 0; vt < 4; ++vt) Oacc[vt] *= alpha;
        Lacc *= alpha;

        // P -> Ps[qrow][key] packed b64 (wave-private rows, lgkmcnt-ordered)
#pragma unroll
        for (int kt = 0; kt < 4; ++kt) {
            uint2 pk;
            pk.x = pkbf(Sv[kt][0], Sv[kt][1]);
            pk.y = pkbf(Sv[kt][2], Sv[kt][3]);
            *(uint2*)&QPs[(w * 16 + l16) * 72 + kt * 16 + quad * 4] = pk;
        }

        // O^T += V^T.P^T ; L += 1.P^T
#pragma unroll
        for (int ks = 0; ks < 2; ++ks) {
            short8 bp = *(const short8*)&QPs[(w * 16 + l16) * 72 + ks * 32 + quad * 8];
            Lacc = __builtin_amdgcn_mfma_f32_16x16x32_bf16(ones, bp, Lacc, 0, 0, 0);
#pragma unroll
            for (int vt = 0; vt < 4; ++vt) {
                short8 av = *(const short8*)&Vt[(vt * 16 + l16) * 72 + ks * 32 + quad * 8];
                Oacc[vt] = __builtin_amdgcn_mfma_f32_16x16x32_bf16(av, bp, Oacc[vt], 0, 0, 0);
            }
        }
    }

    // epilogue: O^T -> Cp[qrow][dim], packed 8B stores
    float inv = 1.0f / Lacc[0];
    int row = q0 + w * 16 + l16;
#pragma unroll
    for (int vt = 0; vt < 4; ++vt) {
        uint2 pk;
        pk.x = pkbf(Oacc[vt][0] * inv, Oacc[vt][1] * inv);
        pk.y = pkbf(Oacc[vt][2] * inv, Oacc[vt][3] * inv);
        *(uint2*)&Cp[(size_t)(b * SEQ + row) * DIMN + h * DH + vt * 16 + quad * 4] = pk;
    }
}

extern "C" void kernel_launch(void* const* d_in, const int* in_sizes, int n_in,
                              void* d_out, int out_size, void* d_ws, size_t ws_size,
                              hipStream_t stream) {
    const float* x_q = (const float*)d_in[0];
    const float* x_k = (const float*)d_in[1];
    const float* x_v = (const float*)d_in[2];
    const int*   msk = (const int*)d_in[3];
    const float* q_w = (const float*)d_in[4];
    const float* q_b = (const float*)d_in[5];
    const float* k_w = (const float*)d_in[6];
    const float* k_b = (const float*)d_in[7];
    const float* v_w = (const float*)d_in[8];
    const float* v_b = (const float*)d_in[9];
    const float* o_w = (const float*)d_in[10];
    const float* o_b = (const float*)d_in[11];
    float* out = (float*)d_out;

    const size_t NEL = (size_t)BSZ * SEQ * DIMN;   // 4 Mi
    const size_t WEL = (size_t)DIMN * DIMN;        // 1 Mi
    // 32 MiB layout: Qp | Kp | VpT | Wq Wk Wv Wo ; Cp aliases Qp (read-before-write)
    ushort_t* Qp  = (ushort_t*)d_ws;
    ushort_t* Kp  = Qp + NEL;
    ushort_t* VpT = Kp + NEL;
    ushort_t* Wq  = VpT + NEL;
    ushort_t* Wk  = Wq + WEL;
    ushort_t* Wv  = Wk + WEL;
    ushort_t* Wo  = Wv + WEL;
    ushort_t* Cp  = Qp;

    cvt_w<<<dim3(WEL / 1024, 4), 256, 0, stream>>>(q_w, k_w, v_w, o_w, Wq, Wk, Wv, Wo);
    gemm_qkv<<<dim3(24, 32), 256, 0, stream>>>(x_q, x_k, x_v, Wq, Wk, Wv,
                                               q_b, k_b, v_b, Qp, Kp, VpT);
    attn_kernel<<<dim3(BSZ * NH, SEQ / 128), 512, 0, stream>>>(Qp, Kp, VpT, msk, Cp);
    gemm_o<<<dim3(16, 32), 256, 0, stream>>>(Cp, Wo, o_b, out);
}